// Round 9
// baseline (2616.528 us; speedup 1.0000x reference)
//
#include <hip/hip_runtime.h>
#include <hip/hip_bf16.h>

// GRU T=1024 B=64 I=256 H=256.
// d_in order: X, W_fx, W_fg, b_fg, W_ix, W_ig, b_ig, W_ux, W_ug, b_ug (all f32)
// d_out: outs [T,B,H] f32 then h_last [B,H] f32.

typedef _Float16 f16x4 __attribute__((ext_vector_type(4)));
typedef _Float16 f16x8 __attribute__((ext_vector_type(8)));
typedef float f32x4 __attribute__((ext_vector_type(4)));
typedef unsigned short u16;
typedef unsigned int u32;

__device__ inline u16 f2bf(float f) {
    u32 u = __float_as_uint(f);
    u = (u + 0x7FFF + ((u >> 16) & 1)) >> 16;   // RNE
    return (u16)u;
}

// MFMA natively consumes AGPRs: wf/wi fragments pinned "+a" (256 AGPRs),
// wu stays "+v" (128 VGPRs). Pins stop LLVM re-sinking the loads into the loop.
__device__ inline void pinA(f16x8& x) { asm volatile("" : "+a"(x)); }
__device__ inline void pinV(f16x8& x) { asm volatile("" : "+v"(x)); }

// Raw workgroup barrier: LDS-visibility only, no vmcnt drain (global
// loads/stores here are thread-private and may stay in flight).
__device__ inline void wg_barrier() {
    asm volatile("s_waitcnt lgkmcnt(0)" ::: "memory");
    __builtin_amdgcn_s_barrier();
    asm volatile("" ::: "memory");
}

// ---------------- prep: WcatT [768][256] bf16: WcatT[g*256+j][k] = Wgx[k][j]
__global__ void prep_wcat(const float* __restrict__ Wfx, const float* __restrict__ Wix,
                          const float* __restrict__ Wux, u16* __restrict__ WcatT) {
    int n = blockIdx.x;            // 0..767
    int k = threadIdx.x;           // 0..255
    int g = n >> 8, j = n & 255;
    const float* W = (g == 0) ? Wfx : (g == 1) ? Wix : Wux;
    WcatT[(size_t)n * 256 + k] = f2bf(W[(size_t)k * 256 + j]);
}

// ---------------- prep: WT f16 [3][256][256]: WT[g][j][i] = Wg[i][j] + bg[j]
__global__ void prep_wrec(const float* __restrict__ Wfg, const float* __restrict__ bfg,
                          const float* __restrict__ Wig, const float* __restrict__ big,
                          const float* __restrict__ Wug, const float* __restrict__ bug,
                          _Float16* __restrict__ WT) {
    int n = blockIdx.x;            // 0..767
    int i = threadIdx.x;           // 0..255
    int g = n >> 8, j = n & 255;
    const float* W = (g == 0) ? Wfg : (g == 1) ? Wig : Wug;
    const float* bv = (g == 0) ? bfg : (g == 1) ? big : bug;
    WT[(size_t)n * 256 + i] = (_Float16)(W[(size_t)i * 256 + j] + bv[j]);
}

// ---------------- projection GEMM: proj[65536][768] f16 = X[65536][256] @ Wcat[256][768]
typedef short bf16x8 __attribute__((ext_vector_type(8)));
__global__ __launch_bounds__(256) void proj_gemm(const float* __restrict__ X,
                                                 const u16* __restrict__ WT, // WcatT [768][256]
                                                 _Float16* __restrict__ proj) {
    __shared__ u16 shA[128][32];
    __shared__ u16 shB[128][32];
    __shared__ _Float16 shC[128][128];

    int tid = threadIdx.x;
    int bn = blockIdx.x % 6, bm = blockIdx.x / 6;
    int lane = tid & 63, wv = tid >> 6;
    int wr = wv >> 1, wc = wv & 1;

    f32x4 acc[4][4];
#pragma unroll
    for (int m = 0; m < 4; m++)
#pragma unroll
        for (int n = 0; n < 4; n++) acc[m][n] = (f32x4){0.f, 0.f, 0.f, 0.f};

    for (int kt = 0; kt < 8; ++kt) {
#pragma unroll
        for (int q = 0; q < 4; ++q) {
            int g = tid + 256 * q;
            int r = g >> 3, c4 = g & 7;
            const float4 v = *(const float4*)(X + (size_t)(bm * 128 + r) * 256 + kt * 32 + c4 * 4);
            ushort4 o;
            o.x = f2bf(v.x); o.y = f2bf(v.y); o.z = f2bf(v.z); o.w = f2bf(v.w);
            *(ushort4*)&shA[r][c4 * 4] = o;
        }
#pragma unroll
        for (int q = 0; q < 2; ++q) {
            int g = tid + 256 * q;
            int r = g >> 2, c8 = g & 3;
            uint4 v = *(const uint4*)(WT + (size_t)(bn * 128 + r) * 256 + kt * 32 + c8 * 8);
            *(uint4*)&shB[r][c8 * 8] = v;
        }
        __syncthreads();

        bf16x8 af[4], bfr[4];
#pragma unroll
        for (int m = 0; m < 4; m++)
            af[m] = *(const bf16x8*)&shA[wr * 64 + m * 16 + (lane & 15)][(lane >> 4) * 8];
#pragma unroll
        for (int n = 0; n < 4; n++)
            bfr[n] = *(const bf16x8*)&shB[wc * 64 + n * 16 + (lane & 15)][(lane >> 4) * 8];
#pragma unroll
        for (int m = 0; m < 4; m++)
#pragma unroll
            for (int n = 0; n < 4; n++)
                acc[m][n] = __builtin_amdgcn_mfma_f32_16x16x32_bf16(af[m], bfr[n], acc[m][n], 0, 0, 0);
        __syncthreads();
    }

#pragma unroll
    for (int m = 0; m < 4; m++)
#pragma unroll
        for (int n = 0; n < 4; n++)
#pragma unroll
            for (int r = 0; r < 4; r++) {
                int row = wr * 64 + m * 16 + (lane >> 4) * 4 + r;
                int col = wc * 64 + n * 16 + (lane & 15);
                shC[row][col] = (_Float16)acc[m][n][r];
            }
    __syncthreads();
    {
        int row = tid >> 1, hf = tid & 1;
        size_t gbase = (size_t)(bm * 128 + row) * 768 + bn * 128 + hf * 64;
        const uint4* src = (const uint4*)&shC[row][hf * 64];
        uint4* dst = (uint4*)(proj + gbase);
#pragma unroll
        for (int q = 0; q < 8; q++) dst[q] = src[q];
    }
}

// ---------------- MFMA recurrence: 4 WGs x 16 batches, 256 threads (4 waves,
// 1 wave/SIMD). D' = W^T h^T per gate; wf/wi AGPR, wu VGPR (weights resident).
// Round-9 changes vs round-8 (which measured: MFMA-pipe 1524 cyc/step busy of
// 5580 total -> ~3300 cyc stalls):
//  * per-jt fusion: each jt's 16 MFMAs immediately followed by its activation
//    + rh/h write, so jt+1's MFMAs overlap jt's VALU/TRANS (separate pipes).
//  * acc-init from x: accF/accI/accU start as cvt(x) (MFMA C-in carries the
//    bias) -- removes 96 zero-movs + 48 adds, frees x regs early.
//  * per-jt acc (8 live f32, not 48) -> reg demand ~240 < 256, no spills.
__global__ __attribute__((amdgpu_flat_work_group_size(256, 256)))
__attribute__((amdgpu_waves_per_eu(1, 1)))
void gru_rec(const _Float16* __restrict__ proj,
             const _Float16* __restrict__ WT,
             float* __restrict__ out) {
    const int tid = threadIdx.x;
    const int wg = blockIdx.x;              // batches [wg*16, wg*16+16)
    const int l = tid & 63, w = tid >> 6;   // wave w owns cols [w*64, w*64+64)
    const int lo = l & 15, hi = l >> 4;

    __shared__ _Float16 h16[16][264];       // h (f16), +8 pad (stride 528B: 2-way banks)
    __shared__ _Float16 rh16[16][264];      // reset*h

    // zero h16 (read at t=0); rh16 fully written each step before read
    for (int idx = tid; idx < 16 * 264 / 8; idx += 256)
        ((uint4*)h16)[idx] = (uint4){0u, 0u, 0u, 0u};

    // weight fragments: frag(g,jt,kt)[e] = WT[g][w*64+jt*16+lo][kt*32+hi*8+e]
    f16x8 wfA[32], wiA[32], wuV[32];
    {
        const _Float16* base = WT + ((size_t)w * 64 + lo) * 256 + hi * 8;
#pragma unroll
        for (int jt = 0; jt < 4; ++jt)
#pragma unroll
            for (int kt = 0; kt < 8; ++kt) {
                size_t off = (size_t)jt * 16 * 256 + (size_t)kt * 32;
                wfA[jt * 8 + kt] = *(const f16x8*)(base + off);
                wiA[jt * 8 + kt] = *(const f16x8*)(base + 65536 + off);
                wuV[jt * 8 + kt] = *(const f16x8*)(base + 131072 + off);
            }
    }
#pragma unroll
    for (int m = 0; m < 32; ++m) { pinA(wfA[m]); pinA(wiA[m]); pinV(wuV[m]); }

    float hreg[4][4];                       // h[m=lo][j = w*64+jt*16+hi*4+r]
#pragma unroll
    for (int jt = 0; jt < 4; ++jt)
#pragma unroll
        for (int r = 0; r < 4; ++r) hreg[jt][r] = 0.f;
    float upd[4][4];

    // x element (g,jt,r) = proj[(t*64+wg*16+lo)*768 + g*256 + w*64+jt*16+hi*4+r]
    const _Float16* xb = proj + ((size_t)wg * 16 + lo) * 768 + w * 64 + hi * 4;
    f16x4 xf4[4], xi4[4], xu4[4];
#pragma unroll
    for (int jt = 0; jt < 4; ++jt) {
        xf4[jt] = *(const f16x4*)(xb + jt * 16);
        xi4[jt] = *(const f16x4*)(xb + 256 + jt * 16);
        xu4[jt] = *(const f16x4*)(xb + 512 + jt * 16);
    }

    float* obase = out + ((size_t)wg * 16 + lo) * 256 + w * 64 + hi * 4;

    __syncthreads();

    for (int t = 0; t < 1024; ++t) {
        // h fragments for this step (8 x ds_read_b128, issued up front)
        f16x8 hb[8];
#pragma unroll
        for (int kt = 0; kt < 8; ++kt)
            hb[kt] = *(const f16x8*)&h16[lo][kt * 32 + hi * 8];

        // ---- F/I phase, fused per jt: 16 MFMA -> act1 -> rh write
#pragma unroll
        for (int jt = 0; jt < 4; ++jt) {
            f32x4 accF, accI;
#pragma unroll
            for (int r = 0; r < 4; ++r) {
                accF[r] = (float)xf4[jt][r];   // bias rides as MFMA C-in
                accI[r] = (float)xi4[jt][r];
            }
#pragma unroll
            for (int kt = 0; kt < 8; ++kt)
                accF = __builtin_amdgcn_mfma_f32_16x16x32_f16(wfA[jt * 8 + kt], hb[kt], accF, 0, 0, 0);
#pragma unroll
            for (int kt = 0; kt < 8; ++kt)
                accI = __builtin_amdgcn_mfma_f32_16x16x32_f16(wiA[jt * 8 + kt], hb[kt], accI, 0, 0, 0);
            f16x4 rhv;
#pragma unroll
            for (int r = 0; r < 4; ++r) {
                float reset = __builtin_amdgcn_rcpf(1.f + __expf(-accF[r]));
                upd[jt][r]  = __builtin_amdgcn_rcpf(1.f + __expf(-accI[r]));
                rhv[r] = (_Float16)(reset * hreg[jt][r]);
            }
            *(f16x4*)&rh16[lo][w * 64 + jt * 16 + hi * 4] = rhv;
        }
        // prefetch next-step xf, xi (in flight across barriers)
        {
            const _Float16* nb = xb + 49152;
#pragma unroll
            for (int jt = 0; jt < 4; ++jt) {
                xf4[jt] = *(const f16x4*)(nb + jt * 16);
                xi4[jt] = *(const f16x4*)(nb + 256 + jt * 16);
            }
        }
        wg_barrier();   // B1: rh visible

        // ---- U phase, fused per jt: 8 MFMA -> act2 -> h write + out store
        f16x8 rb[8];
#pragma unroll
        for (int kt = 0; kt < 8; ++kt)
            rb[kt] = *(const f16x8*)&rh16[lo][kt * 32 + hi * 8];
#pragma unroll
        for (int jt = 0; jt < 4; ++jt) {
            f32x4 accU;
#pragma unroll
            for (int r = 0; r < 4; ++r) accU[r] = (float)xu4[jt][r];
#pragma unroll
            for (int kt = 0; kt < 8; ++kt)
                accU = __builtin_amdgcn_mfma_f32_16x16x32_f16(wuV[jt * 8 + kt], rb[kt], accU, 0, 0, 0);
            f16x4 hv; f32x4 ov;
#pragma unroll
            for (int r = 0; r < 4; ++r) {
                float e2 = __expf(2.f * accU[r]);
                float cand = (e2 - 1.f) * __builtin_amdgcn_rcpf(e2 + 1.f);
                float hn = upd[jt][r] * hreg[jt][r] + (1.f - upd[jt][r]) * cand;
                hreg[jt][r] = hn;
                hv[r] = (_Float16)hn;
                ov[r] = hn;
            }
            *(f16x4*)&h16[lo][w * 64 + jt * 16 + hi * 4] = hv;
            *(f32x4*)(obase + jt * 16) = ov;
        }
        // prefetch next-step xu
        {
            const _Float16* nb = xb + 49152 + 512;
#pragma unroll
            for (int jt = 0; jt < 4; ++jt) xu4[jt] = *(const f16x4*)(nb + jt * 16);
        }
        xb += 49152;
        obase += 16384;
        wg_barrier();   // B2: h visible
    }

    // h_last
    float* hp = out + (size_t)16777216 + ((size_t)wg * 16 + lo) * 256 + w * 64 + hi * 4;
#pragma unroll
    for (int jt = 0; jt < 4; ++jt) {
        f32x4 hv;
#pragma unroll
        for (int r = 0; r < 4; ++r) hv[r] = hreg[jt][r];
        *(f32x4*)(hp + jt * 16) = hv;
    }
}

extern "C" void kernel_launch(void* const* d_in, const int* in_sizes, int n_in,
                              void* d_out, int out_size, void* d_ws, size_t ws_size,
                              hipStream_t stream) {
    const float* X   = (const float*)d_in[0];
    const float* Wfx = (const float*)d_in[1];
    const float* Wfg = (const float*)d_in[2];
    const float* bfg = (const float*)d_in[3];
    const float* Wix = (const float*)d_in[4];
    const float* Wig = (const float*)d_in[5];
    const float* big = (const float*)d_in[6];
    const float* Wux = (const float*)d_in[7];
    const float* Wug = (const float*)d_in[8];
    const float* bug = (const float*)d_in[9];
    float* out = (float*)d_out;

    char* ws = (char*)d_ws;
    _Float16* proj = (_Float16*)ws;                          // 65536*768*2 = 100663296 B
    u16* WcatT = (u16*)(ws + 100663296);                     // 768*256*2   = 393216 B
    _Float16* WT = (_Float16*)(ws + 100663296 + 393216);     // 3*256*256*2 = 393216 B

    prep_wcat<<<768, 256, 0, stream>>>(Wfx, Wix, Wux, WcatT);
    prep_wrec<<<768, 256, 0, stream>>>(Wfg, bfg, Wig, big, Wug, bug, WT);
    proj_gemm<<<3072, 256, 0, stream>>>(X, WcatT, proj);
    gru_rec<<<4, 256, 0, stream>>>(proj, WT, out);
}

// Round 11
// 2092.419 us; speedup vs baseline: 1.2505x; 1.2505x over previous
//
#include <hip/hip_runtime.h>
#include <hip/hip_bf16.h>

// GRU T=1024 B=64 I=256 H=256.
// d_in order: X, W_fx, W_fg, b_fg, W_ix, W_ig, b_ig, W_ux, W_ug, b_ug (all f32)
// d_out: outs [T,B,H] f32 then h_last [B,H] f32.

typedef _Float16 f16x4 __attribute__((ext_vector_type(4)));
typedef _Float16 f16x8 __attribute__((ext_vector_type(8)));
typedef float f32x4 __attribute__((ext_vector_type(4)));
typedef unsigned short u16;
typedef unsigned int u32;

__device__ inline u16 f2bf(float f) {
    u32 u = __float_as_uint(f);
    u = (u + 0x7FFF + ((u >> 16) & 1)) >> 16;   // RNE
    return (u16)u;
}

// "+v" pin: keeps loaded weight values in VGPRs, stops LLVM re-sinking the
// loads into the loop. (Round 10: "+a" pins at an infeasible budget -> RA
// spilled pinned AGPR tuples -> corrupted weights -> NaN. All-VGPR now,
// demand ~230 < 256-reg budget at 2 waves/SIMD.)
__device__ inline void pinV(f16x8& x) { asm volatile("" : "+v"(x)); }

// Raw workgroup barrier: LDS-visibility only, no vmcnt drain (global
// loads/stores here are thread-private and may stay in flight).
__device__ inline void wg_barrier() {
    asm volatile("s_waitcnt lgkmcnt(0)" ::: "memory");
    __builtin_amdgcn_s_barrier();
    asm volatile("" ::: "memory");
}

// ---------------- prep: WcatT [768][256] bf16: WcatT[g*256+j][k] = Wgx[k][j]
__global__ void prep_wcat(const float* __restrict__ Wfx, const float* __restrict__ Wix,
                          const float* __restrict__ Wux, u16* __restrict__ WcatT) {
    int n = blockIdx.x;            // 0..767
    int k = threadIdx.x;           // 0..255
    int g = n >> 8, j = n & 255;
    const float* W = (g == 0) ? Wfx : (g == 1) ? Wix : Wux;
    WcatT[(size_t)n * 256 + k] = f2bf(W[(size_t)k * 256 + j]);
}

// ---------------- prep: WT f16 [3][256][256]: WT[g][j][i] = Wg[i][j] + bg[j]
__global__ void prep_wrec(const float* __restrict__ Wfg, const float* __restrict__ bfg,
                          const float* __restrict__ Wig, const float* __restrict__ big,
                          const float* __restrict__ Wug, const float* __restrict__ bug,
                          _Float16* __restrict__ WT) {
    int n = blockIdx.x;            // 0..767
    int i = threadIdx.x;           // 0..255
    int g = n >> 8, j = n & 255;
    const float* W = (g == 0) ? Wfg : (g == 1) ? Wig : Wug;
    const float* bv = (g == 0) ? bfg : (g == 1) ? big : bug;
    WT[(size_t)n * 256 + i] = (_Float16)(W[(size_t)i * 256 + j] + bv[j]);
}

// ---------------- projection GEMM: proj[65536][768] f16 = X[65536][256] @ Wcat[256][768]
typedef short bf16x8 __attribute__((ext_vector_type(8)));
__global__ __launch_bounds__(256) void proj_gemm(const float* __restrict__ X,
                                                 const u16* __restrict__ WT, // WcatT [768][256]
                                                 _Float16* __restrict__ proj) {
    __shared__ u16 shA[128][32];
    __shared__ u16 shB[128][32];
    __shared__ _Float16 shC[128][128];

    int tid = threadIdx.x;
    int bn = blockIdx.x % 6, bm = blockIdx.x / 6;
    int lane = tid & 63, wv = tid >> 6;
    int wr = wv >> 1, wc = wv & 1;

    f32x4 acc[4][4];
#pragma unroll
    for (int m = 0; m < 4; m++)
#pragma unroll
        for (int n = 0; n < 4; n++) acc[m][n] = (f32x4){0.f, 0.f, 0.f, 0.f};

    for (int kt = 0; kt < 8; ++kt) {
#pragma unroll
        for (int q = 0; q < 4; ++q) {
            int g = tid + 256 * q;
            int r = g >> 3, c4 = g & 7;
            const float4 v = *(const float4*)(X + (size_t)(bm * 128 + r) * 256 + kt * 32 + c4 * 4);
            ushort4 o;
            o.x = f2bf(v.x); o.y = f2bf(v.y); o.z = f2bf(v.z); o.w = f2bf(v.w);
            *(ushort4*)&shA[r][c4 * 4] = o;
        }
#pragma unroll
        for (int q = 0; q < 2; ++q) {
            int g = tid + 256 * q;
            int r = g >> 2, c8 = g & 3;
            uint4 v = *(const uint4*)(WT + (size_t)(bn * 128 + r) * 256 + kt * 32 + c8 * 8);
            *(uint4*)&shB[r][c8 * 8] = v;
        }
        __syncthreads();

        bf16x8 af[4], bfr[4];
#pragma unroll
        for (int m = 0; m < 4; m++)
            af[m] = *(const bf16x8*)&shA[wr * 64 + m * 16 + (lane & 15)][(lane >> 4) * 8];
#pragma unroll
        for (int n = 0; n < 4; n++)
            bfr[n] = *(const bf16x8*)&shB[wc * 64 + n * 16 + (lane & 15)][(lane >> 4) * 8];
#pragma unroll
        for (int m = 0; m < 4; m++)
#pragma unroll
            for (int n = 0; n < 4; n++)
                acc[m][n] = __builtin_amdgcn_mfma_f32_16x16x32_bf16(af[m], bfr[n], acc[m][n], 0, 0, 0);
        __syncthreads();
    }

#pragma unroll
    for (int m = 0; m < 4; m++)
#pragma unroll
        for (int n = 0; n < 4; n++)
#pragma unroll
            for (int r = 0; r < 4; r++) {
                int row = wr * 64 + m * 16 + (lane >> 4) * 4 + r;
                int col = wc * 64 + n * 16 + (lane & 15);
                shC[row][col] = (_Float16)acc[m][n][r];
            }
    __syncthreads();
    {
        int row = tid >> 1, hf = tid & 1;
        size_t gbase = (size_t)(bm * 128 + row) * 768 + bn * 128 + hf * 64;
        const uint4* src = (const uint4*)&shC[row][hf * 64];
        uint4* dst = (uint4*)(proj + gbase);
#pragma unroll
        for (int q = 0; q < 8; q++) dst[q] = src[q];
    }
}

// ---------------- MFMA recurrence: 4 WGs x 16 batches, 512 threads = 8 waves
// = 2 waves/SIMD (so MFMA issue and VALU/activation work of the two waves
// overlap instead of serializing on one wave's issue port — round 8/9 ran
// 1 wave/SIMD and paid ~3x the MFMA floor). Wave w owns cols [w*32,w*32+32).
// Weights: wf,wi = 32 f16x8 frags = 128 VGPRs, "+v"-pinned (fits the 2-wave
// 256-reg budget with ~100 live regs; NO AGPR pins — round 10's NaN).
// wu streamed from LDS (wuL[256][264], 132 KB) each U phase: +16 b128/thread
// on the LDS pipe, hidden under the MFMA floor.
__global__ __attribute__((amdgpu_flat_work_group_size(512, 512)))
__attribute__((amdgpu_waves_per_eu(2, 2)))
void gru_rec(const _Float16* __restrict__ proj,
             const _Float16* __restrict__ WT,
             float* __restrict__ out) {
    const int tid = threadIdx.x;
    const int wg = blockIdx.x;              // batches [wg*16, wg*16+16)
    const int l = tid & 63, w = tid >> 6;   // wave w owns cols [w*32, w*32+32)
    const int lo = l & 15, hi = l >> 4;
    const int cbase = w * 32;

    __shared__ _Float16 wuL[256][264];      // u-gate weights, row j, +8 pad (132 KB)
    __shared__ _Float16 h16[16][264];       // h (f16), row = batch, +8 pad
    __shared__ _Float16 rh16[16][264];      // reset*h

    // stage wu into LDS: wuL[j][i] = WT[2][j][i]; 2 threads per row
    {
        int row = tid >> 1, half = tid & 1;
        const uint4* src = (const uint4*)(WT + 131072 + (size_t)row * 256 + half * 128);
        uint4* dst = (uint4*)&wuL[row][half * 128];
#pragma unroll
        for (int q = 0; q < 16; ++q) dst[q] = src[q];
    }
    // zero h16 (read at t=0); rh16 fully written each step before read
    for (int idx = tid; idx < 16 * 264 * 2 / 16; idx += 512)
        ((uint4*)h16)[idx] = (uint4){0u, 0u, 0u, 0u};

    // f,i weight fragments: frag(g,jt,kt)[e] = WT[g][cbase+jt*16+lo][kt*32+hi*8+e]
    f16x8 wfV[16], wiV[16];
    {
        const _Float16* base = WT + ((size_t)cbase + lo) * 256 + hi * 8;
#pragma unroll
        for (int jt = 0; jt < 2; ++jt)
#pragma unroll
            for (int kt = 0; kt < 8; ++kt) {
                size_t off = (size_t)jt * 16 * 256 + (size_t)kt * 32;
                wfV[jt * 8 + kt] = *(const f16x8*)(base + off);
                wiV[jt * 8 + kt] = *(const f16x8*)(base + 65536 + off);
            }
    }
#pragma unroll
    for (int m = 0; m < 16; ++m) { pinV(wfV[m]); pinV(wiV[m]); }

    float hreg[2][4];                       // h[m=lo][j = cbase+jt*16+hi*4+r]
#pragma unroll
    for (int jt = 0; jt < 2; ++jt)
#pragma unroll
        for (int r = 0; r < 4; ++r) hreg[jt][r] = 0.f;
    float upd[2][4];

    // x element (g,jt,r) = proj[(t*64+wg*16+lo)*768 + g*256 + cbase+jt*16+hi*4+r]
    const _Float16* xb = proj + ((size_t)wg * 16 + lo) * 768 + cbase + hi * 4;
    f16x4 xf4[2], xi4[2], xu4[2];
#pragma unroll
    for (int jt = 0; jt < 2; ++jt) {
        xf4[jt] = *(const f16x4*)(xb + jt * 16);
        xi4[jt] = *(const f16x4*)(xb + 256 + jt * 16);
        xu4[jt] = *(const f16x4*)(xb + 512 + jt * 16);
    }

    float* obase = out + ((size_t)wg * 16 + lo) * 256 + cbase + hi * 4;

    __syncthreads();

    for (int t = 0; t < 1024; ++t) {
        // ---- F/I phase
        f16x8 hb[8];
#pragma unroll
        for (int kt = 0; kt < 8; ++kt)
            hb[kt] = *(const f16x8*)&h16[lo][kt * 32 + hi * 8];

        f32x4 accF[2], accI[2];
#pragma unroll
        for (int jt = 0; jt < 2; ++jt)
#pragma unroll
            for (int r = 0; r < 4; ++r) {
                accF[jt][r] = (float)xf4[jt][r];   // bias rides as MFMA C-in
                accI[jt][r] = (float)xi4[jt][r];
            }
        __builtin_amdgcn_s_setprio(1);
#pragma unroll
        for (int kt = 0; kt < 8; ++kt)
#pragma unroll
            for (int jt = 0; jt < 2; ++jt) {
                accF[jt] = __builtin_amdgcn_mfma_f32_16x16x32_f16(wfV[jt * 8 + kt], hb[kt], accF[jt], 0, 0, 0);
                accI[jt] = __builtin_amdgcn_mfma_f32_16x16x32_f16(wiV[jt * 8 + kt], hb[kt], accI[jt], 0, 0, 0);
            }
        __builtin_amdgcn_s_setprio(0);

        // prefetch next-step xf, xi (stay in flight across the barrier)
        {
            const _Float16* nb = xb + 49152;
#pragma unroll
            for (int jt = 0; jt < 2; ++jt) {
                xf4[jt] = *(const f16x4*)(nb + jt * 16);
                xi4[jt] = *(const f16x4*)(nb + 256 + jt * 16);
            }
        }
#pragma unroll
        for (int jt = 0; jt < 2; ++jt) {
            f16x4 rhv;
#pragma unroll
            for (int r = 0; r < 4; ++r) {
                float reset = __builtin_amdgcn_rcpf(1.f + __expf(-accF[jt][r]));
                upd[jt][r]  = __builtin_amdgcn_rcpf(1.f + __expf(-accI[jt][r]));
                rhv[r] = (_Float16)(reset * hreg[jt][r]);
            }
            *(f16x4*)&rh16[lo][cbase + jt * 16 + hi * 4] = rhv;
        }
        wg_barrier();   // B1: rh visible

        // ---- U phase: A-frags streamed from LDS, interleaved with MFMA
        f16x8 rb[8];
#pragma unroll
        for (int kt = 0; kt < 8; ++kt)
            rb[kt] = *(const f16x8*)&rh16[lo][kt * 32 + hi * 8];

        f32x4 accU[2];
#pragma unroll
        for (int jt = 0; jt < 2; ++jt)
#pragma unroll
            for (int r = 0; r < 4; ++r) accU[jt][r] = (float)xu4[jt][r];
        __builtin_amdgcn_s_setprio(1);
#pragma unroll
        for (int kt = 0; kt < 8; ++kt) {
            f16x8 wu0 = *(const f16x8*)&wuL[cbase + lo][kt * 32 + hi * 8];
            f16x8 wu1 = *(const f16x8*)&wuL[cbase + 16 + lo][kt * 32 + hi * 8];
            accU[0] = __builtin_amdgcn_mfma_f32_16x16x32_f16(wu0, rb[kt], accU[0], 0, 0, 0);
            accU[1] = __builtin_amdgcn_mfma_f32_16x16x32_f16(wu1, rb[kt], accU[1], 0, 0, 0);
        }
        __builtin_amdgcn_s_setprio(0);

        // prefetch next-step xu
        {
            const _Float16* nb = xb + 49152 + 512;
#pragma unroll
            for (int jt = 0; jt < 2; ++jt) xu4[jt] = *(const f16x4*)(nb + jt * 16);
        }
#pragma unroll
        for (int jt = 0; jt < 2; ++jt) {
            f16x4 hv; f32x4 ov;
#pragma unroll
            for (int r = 0; r < 4; ++r) {
                float z = accU[jt][r];
                // NaN-safe tanh: e in (0,1], no inf*0 path
                float e = __expf(-2.f * __builtin_fabsf(z));
                float tm = (1.f - e) * __builtin_amdgcn_rcpf(1.f + e);
                float cand = __builtin_copysignf(tm, z);
                float hn = upd[jt][r] * hreg[jt][r] + (1.f - upd[jt][r]) * cand;
                hreg[jt][r] = hn;
                hv[r] = (_Float16)hn;
                ov[r] = hn;
            }
            *(f16x4*)&h16[lo][cbase + jt * 16 + hi * 4] = hv;
            *(f32x4*)(obase + jt * 16) = ov;
        }
        xb += 49152;
        obase += 16384;
        wg_barrier();   // B2: h visible
    }

    // h_last
    float* hp = out + (size_t)16777216 + ((size_t)wg * 16 + lo) * 256 + cbase + hi * 4;
#pragma unroll
    for (int jt = 0; jt < 2; ++jt) {
        f32x4 hv;
#pragma unroll
        for (int r = 0; r < 4; ++r) hv[r] = hreg[jt][r];
        *(f32x4*)(hp + jt * 16) = hv;
    }
}

extern "C" void kernel_launch(void* const* d_in, const int* in_sizes, int n_in,
                              void* d_out, int out_size, void* d_ws, size_t ws_size,
                              hipStream_t stream) {
    const float* X   = (const float*)d_in[0];
    const float* Wfx = (const float*)d_in[1];
    const float* Wfg = (const float*)d_in[2];
    const float* bfg = (const float*)d_in[3];
    const float* Wix = (const float*)d_in[4];
    const float* Wig = (const float*)d_in[5];
    const float* big = (const float*)d_in[6];
    const float* Wux = (const float*)d_in[7];
    const float* Wug = (const float*)d_in[8];
    const float* bug = (const float*)d_in[9];
    float* out = (float*)d_out;

    char* ws = (char*)d_ws;
    _Float16* proj = (_Float16*)ws;                          // 65536*768*2 = 100663296 B
    u16* WcatT = (u16*)(ws + 100663296);                     // 768*256*2   = 393216 B
    _Float16* WT = (_Float16*)(ws + 100663296 + 393216);     // 3*256*256*2 = 393216 B

    prep_wcat<<<768, 256, 0, stream>>>(Wfx, Wix, Wux, WcatT);
    prep_wrec<<<768, 256, 0, stream>>>(Wfg, bfg, Wig, big, Wug, bug, WT);
    proj_gemm<<<3072, 256, 0, stream>>>(X, WcatT, proj);
    gru_rec<<<4, 512, 0, stream>>>(proj, WT, out);
}